// Round 1
// baseline (318.332 us; speedup 1.0000x reference)
//
#include <hip/hip_runtime.h>

typedef __bf16 bf16x8 __attribute__((ext_vector_type(8)));
typedef float  f32x4  __attribute__((ext_vector_type(4)));
typedef unsigned short u16x8 __attribute__((ext_vector_type(8)));
typedef unsigned short USHORT;

__device__ __forceinline__ USHORT f2bf(float f) {
    unsigned u = __float_as_uint(f);
    u += 0x7fffu + ((u >> 16) & 1u);
    return (USHORT)(u >> 16);
}

__device__ __forceinline__ f32x4 fz4() { f32x4 z = {0.f, 0.f, 0.f, 0.f}; return z; }

__device__ __forceinline__ bf16x8 ldbf8(const USHORT* p) { return *(const bf16x8*)p; }

__device__ __forceinline__ f32x4 mfma16(bf16x8 a, bf16x8 b, f32x4 c) {
    return __builtin_amdgcn_mfma_f32_16x16x32_bf16(a, b, c, 0, 0, 0);
}

// async global->LDS, 16B per lane; LDS dest is wave-uniform base + lane*16
__device__ __forceinline__ void gload_lds16(const void* g, void* s) {
    __builtin_amdgcn_global_load_lds(
        (const __attribute__((address_space(1))) unsigned int*)g,
        (__attribute__((address_space(3))) unsigned int*)s, 16, 0, 0);
}

// per-wave LDS ordering fence (wave-private LDS region; no cross-wave barrier
// needed). "memory" clobber keeps the compiler from hoisting ds ops across.
__device__ __forceinline__ void lds_fence() {
    asm volatile("s_waitcnt lgkmcnt(0)" ::: "memory");
    __builtin_amdgcn_sched_barrier(0);
}

// ---------------- merged prep: X fp32->bf16 + both W transposes ----------------
// blocks [0,2048): X cvt (8 elems/thread). [2048,3328): Wqkv^T. [3328,4352): Wout^T.
__global__ __launch_bounds__(256) void prep_kernel(const float* __restrict__ X,
                                                   const float* __restrict__ Wqkv,
                                                   const float* __restrict__ Wout,
                                                   USHORT* __restrict__ Xb,
                                                   USHORT* __restrict__ Wt1,
                                                   USHORT* __restrict__ Wt3) {
    int bid = blockIdx.x;
    if (bid < 2048) {
        int base = (bid * 256 + threadIdx.x) * 8;
        float4 a = *(const float4*)(X + base);
        float4 b = *(const float4*)(X + base + 4);
        u16x8 o;
        o[0] = f2bf(a.x); o[1] = f2bf(a.y); o[2] = f2bf(a.z); o[3] = f2bf(a.w);
        o[4] = f2bf(b.x); o[5] = f2bf(b.y); o[6] = f2bf(b.z); o[7] = f2bf(b.w);
        *(u16x8*)(Xb + base) = o;
    } else if (bid < 3328) {
        int t = (bid - 2048) * 256 + threadIdx.x;   // 0..327679 : 640x512
        int k = t & 511, n = t >> 9;
        Wt1[t] = f2bf(Wqkv[(size_t)k * 1536 + n]);
    } else {
        int t = (bid - 3328) * 256 + threadIdx.x;   // 0..262143 : 512x512
        int k = t & 511, n = t >> 9;
        Wt3[t] = f2bf(Wout[(size_t)k * 512 + n]);
    }
}

// ---------------- m97-style bf16 GEMM: C = A(MxK) * Bt(NxK)^T -------------------
// BM=BN=128, BK=32, 256 threads (4 waves), global_load_lds width-16 staging.
template <bool BF16OUT>
__global__ __launch_bounds__(256) void gemm_bt(const USHORT* __restrict__ A,
                                               const USHORT* __restrict__ Bt,
                                               void* __restrict__ Cv,
                                               int M, int N, int K) {
    __shared__ __align__(16) USHORT Asm[128 * 32];
    __shared__ __align__(16) USHORT Bsm[128 * 32];
    const int tid = threadIdx.x;
    const int wv = tid >> 6, ln = tid & 63;
    const int l16 = ln & 15, quad = ln >> 4;
    const int m0 = blockIdx.x * 128, n0 = blockIdx.y * 128;
    const int wm = (wv >> 1) * 64, wn = (wv & 1) * 64;

    f32x4 acc[4][4];
#pragma unroll
    for (int i = 0; i < 4; ++i)
#pragma unroll
        for (int j = 0; j < 4; ++j) acc[i][j] = fz4();

    const int kTiles = K >> 5;
    for (int kt = 0; kt < kTiles; ++kt) {
        __syncthreads();  // protect LDS reuse from previous iter
#pragma unroll
        for (int i = 0; i < 2; ++i) {
            int cb = wv * 128 + i * 64;   // wave-uniform chunk base
            int c = cb + ln;              // chunk: row=c>>2, 16B piece=(c&3)
            gload_lds16(A + (size_t)(m0 + (c >> 2)) * K + kt * 32 + (c & 3) * 8,
                        &Asm[cb * 8]);
            gload_lds16(Bt + (size_t)(n0 + (c >> 2)) * K + kt * 32 + (c & 3) * 8,
                        &Bsm[cb * 8]);
        }
        __syncthreads();  // drains vmcnt for global_load_lds

        bf16x8 af[4], bfr[4];
#pragma unroll
        for (int i = 0; i < 4; ++i)
            af[i] = ldbf8(&Asm[(wm + i * 16 + l16) * 32 + quad * 8]);
#pragma unroll
        for (int j = 0; j < 4; ++j)
            bfr[j] = ldbf8(&Bsm[(wn + j * 16 + l16) * 32 + quad * 8]);
#pragma unroll
        for (int i = 0; i < 4; ++i)
#pragma unroll
            for (int j = 0; j < 4; ++j)
                acc[i][j] = mfma16(af[i], bfr[j], acc[i][j]);
    }

    // epilogue: C/D layout col=lane&15, row=quad*4+reg (m89-verified)
#pragma unroll
    for (int i = 0; i < 4; ++i)
#pragma unroll
        for (int j = 0; j < 4; ++j)
#pragma unroll
            for (int r = 0; r < 4; ++r) {
                size_t row = m0 + wm + i * 16 + quad * 4 + r;
                size_t col = n0 + wn + j * 16 + l16;
                if (BF16OUT)
                    ((USHORT*)Cv)[row * N + col] = f2bf(acc[i][j][r]);
                else
                    ((float*)Cv)[row * N + col] = acc[i][j][r];
            }
}

// ---------------- V transpose: Vt[((b*8+h)*64+d)*1024+k] = P[(b*1024+k)*640+(h+2)*64+d]
__global__ __launch_bounds__(256) void transpose_v(const USHORT* __restrict__ P,
                                                   USHORT* __restrict__ Vt) {
    __shared__ __align__(16) USHORT T[64][72];  // pad to break bank conflicts
    const int t = threadIdx.x;
    const int k0 = blockIdx.x * 64;
    const int hh = blockIdx.y;
    const int b = blockIdx.z;
#pragma unroll
    for (int i = 0; i < 2; ++i) {
        int c = i * 256 + t;  // 0..511 : 64 k-rows x 8 chunks of 8 d
        int kk = c >> 3, d8 = (c & 7) * 8;
        u16x8 v = *(const u16x8*)(P + (size_t)((b << 10) + k0 + kk) * 640 +
                                  (hh + 2) * 64 + d8);
        *(u16x8*)&T[kk][d8] = v;
    }
    __syncthreads();
#pragma unroll
    for (int i = 0; i < 2; ++i) {
        int d = (t >> 3) + i * 32;
        int kk0 = (t & 7) * 8;
        u16x8 v;
#pragma unroll
        for (int j = 0; j < 8; ++j) v[j] = T[kk0 + j][d];
        *(u16x8*)(Vt + (size_t)(((b << 3) + hh) * 64 + d) * 1024 + k0 + kk0) = v;
    }
}

// ---------------- fused attention v3 ------------------------------------------
// 4 waves per WG; wave wv owns k-chunk wv (256 keys). grid = (h=8, qtile=64)
// = 512 blocks x 4 waves = 2048 waves (2/SIMD, same as v2).
// Waves are INDEPENDENT through the k-loop (wave-private attn_lds slice +
// per-wave lgkmcnt fences instead of barriers — no lockstep coupling).
// Epilogue: partial oacc summed across the 4 waves via LDS ds_add_f32
// (pad stride 84 floats -> 2-way bank alias = free), then ONE bf16 store
// per ctx element. Replaces 16.8M global fp32 atomics (67MB HBM write-through)
// + ctx memset + cvt kernel.
__global__ __launch_bounds__(256) void attn_kernel(const USHORT* __restrict__ P,
                                                   const USHORT* __restrict__ Vt,
                                                   USHORT* __restrict__ CtxB) {
    const int h = blockIdx.x;
    const int q0 = blockIdx.y * 16;
    const int tid = threadIdx.x;
    const int wv = tid >> 6;                    // k-chunk 0..3 (256 keys each)
    const int lane = tid & 63;
    const int l16 = lane & 15, quad = lane >> 4;

    // union: per-wave attn transpose slices (4 x 10240B) / reduce tile (43008B)
    __shared__ __align__(16) char smem[43008];
    USHORT (*alds)[16][40] = (USHORT (*)[16][40])(smem + wv * 10240);

    // Q fragments: A[m=l16][k=quad*8+j] (k = head dim, 2 ksteps of 32)
    bf16x8 qf[8][2];
#pragma unroll
    for (int b = 0; b < 8; ++b)
#pragma unroll
        for (int ks = 0; ks < 2; ++ks)
            qf[b][ks] = ldbf8(P + (size_t)((b << 10) + q0 + l16) * 640 + h * 64 +
                              ks * 32 + quad * 8);

    f32x4 oacc[8][4];
#pragma unroll
    for (int b = 0; b < 8; ++b)
#pragma unroll
        for (int nt = 0; nt < 4; ++nt) oacc[b][nt] = fz4();

    for (int it = 0; it < 8; ++it) {
        const int k0 = wv * 256 + it * 32;

        // ---- scores: all 8 batches at matching register positions ----
        f32x4 sacc[8][2];
#pragma unroll
        for (int b = 0; b < 8; ++b) { sacc[b][0] = fz4(); sacc[b][1] = fz4(); }
#pragma unroll
        for (int ks = 0; ks < 2; ++ks)
#pragma unroll
            for (int nt = 0; nt < 2; ++nt) {
                bf16x8 kf[8];  // batch loads: 8 in flight before first use
#pragma unroll
                for (int b = 0; b < 8; ++b)
                    kf[b] = ldbf8(P + (size_t)((b << 10) + k0 + nt * 16 + l16) * 640 +
                                  (h + 1) * 64 + ks * 32 + quad * 8);
#pragma unroll
                for (int b = 0; b < 8; ++b)
                    sacc[b][nt] = mfma16(qf[b][ks], kf[b], sacc[b][nt]);
            }

        // ---- softmax over batch axis: per-lane; no max pass needed ----
        // scores*scale ~ N(0,0.2^2): exp2 arg |x| < 2 even at 8 sigma.
#pragma unroll
        for (int nt = 0; nt < 2; ++nt)
#pragma unroll
            for (int r = 0; r < 4; ++r) {
                float e[8];
                float Z = 0.f;
#pragma unroll
                for (int b = 0; b < 8; ++b) {
                    // 0.125 (1/sqrt(64)) * log2(e)
                    e[b] = __builtin_amdgcn_exp2f(sacc[b][nt][r] * 0.1803368801f);
                    Z += e[b];
                }
                float inv = __builtin_amdgcn_rcpf(Z);
#pragma unroll
                for (int b = 0; b < 8; ++b)
                    alds[b][quad * 4 + r][nt * 16 + l16] = f2bf(e[b] * inv);
            }
        lds_fence();  // wave-private region: order ds_write -> ds_read

        // ---- PV: A=attn[16x32] (LDS, A-layout), B=V^T fragments ----
#pragma unroll
        for (int b = 0; b < 8; ++b) {
            bf16x8 af = *(const bf16x8*)&alds[b][l16][quad * 8];
            bf16x8 vf[4];  // batch loads
#pragma unroll
            for (int nt = 0; nt < 4; ++nt)
                vf[nt] = ldbf8(Vt + (size_t)(((b << 3) + h) * 64 + nt * 16 + l16) * 1024 +
                               k0 + quad * 8);
#pragma unroll
            for (int nt = 0; nt < 4; ++nt)
                oacc[b][nt] = mfma16(af, vf[nt], oacc[b][nt]);
        }
        lds_fence();  // order ds_read -> next iter's ds_write
    }

    // ---- cross-wave reduction in LDS (replaces global atomics) ----
    __syncthreads();  // all waves done with alds; reuse smem as fp32 tile
    float (*red)[16][84] = (float (*)[16][84])smem;  // stride 84: 2-way alias only
    float* rf = (float*)smem;
#pragma unroll
    for (int i = 0; i < 42; ++i) rf[i * 256 + tid] = 0.f;  // 42*256 = 10752 floats
    __syncthreads();
#pragma unroll
    for (int b = 0; b < 8; ++b)
#pragma unroll
        for (int nt = 0; nt < 4; ++nt)
#pragma unroll
            for (int r = 0; r < 4; ++r)
                atomicAdd(&red[b][quad * 4 + r][nt * 16 + l16], oacc[b][nt][r]);
    __syncthreads();

    // ---- store bf16 ctx tile: 8b x 16q x 64d; thread -> (b, q, 32d) ----
    {
        const int b = tid >> 5;            // 0..7
        const int qq = (tid >> 1) & 15;    // 0..15
        const int d0 = (tid & 1) * 32;
        const float* src = &red[b][qq][d0];
        size_t row = ((size_t)b << 10) + q0 + qq;
        USHORT* dst = CtxB + row * 512 + h * 64 + d0;
#pragma unroll
        for (int j = 0; j < 4; ++j) {
            f32x4 a = *(const f32x4*)(src + j * 8);
            f32x4 c = *(const f32x4*)(src + j * 8 + 4);
            u16x8 o;
            o[0] = f2bf(a[0]); o[1] = f2bf(a[1]); o[2] = f2bf(a[2]); o[3] = f2bf(a[3]);
            o[4] = f2bf(c[0]); o[5] = f2bf(c[1]); o[6] = f2bf(c[2]); o[7] = f2bf(c[3]);
            *(u16x8*)(dst + j * 8) = o;
        }
    }
}

extern "C" void kernel_launch(void* const* d_in, const int* in_sizes, int n_in,
                              void* d_out, int out_size, void* d_ws, size_t ws_size,
                              hipStream_t stream) {
    const float* X = (const float*)d_in[0];     // (8,1024,512)
    const float* Wqkv = (const float*)d_in[1];  // (512,1536) — only cols 0..639 used
    const float* Wout = (const float*)d_in[2];  // (512,512)
    float* out = (float*)d_out;                 // (8,1024,512) fp32

    char* w = (char*)d_ws;
    USHORT* Xb  = (USHORT*)(w);              //  8,388,608 B (reused as CtxB later)
    USHORT* Wt1 = (USHORT*)(w + 8388608);    //    655,360 B  (640x512)
    USHORT* Wt3 = (USHORT*)(w + 9043968);    //    524,288 B  (512x512)
    USHORT* P   = (USHORT*)(w + 9568256);    // 10,485,760 B  (8192x640 bf16)
    USHORT* Vt  = (USHORT*)(w + 20054016);   //  8,388,608 B  (8x8x64x1024 bf16)
    USHORT* CtxB = Xb;                       // Xb dead after GEMM1; 8192x512 bf16

    prep_kernel<<<4352, 256, 0, stream>>>(X, Wqkv, Wout, Xb, Wt1, Wt3);
    // P = Xb @ Wqkv[:, :640]
    gemm_bt<true><<<dim3(64, 5), 256, 0, stream>>>(Xb, Wt1, (void*)P, 8192, 640, 512);
    transpose_v<<<dim3(16, 8, 8), 256, 0, stream>>>(P, Vt);
    // attention writes bf16 ctx directly (no global atomics, no memset, no cvt)
    attn_kernel<<<dim3(8, 64), 256, 0, stream>>>(P, Vt, CtxB);
    // out = ctx @ W_out
    gemm_bt<false><<<dim3(64, 4), 256, 0, stream>>>(CtxB, Wt3, (void*)out, 8192, 512, 512);
}

// Round 3
// 285.437 us; speedup vs baseline: 1.1152x; 1.1152x over previous
//
#include <hip/hip_runtime.h>

typedef __bf16 bf16x8 __attribute__((ext_vector_type(8)));
typedef float  f32x4  __attribute__((ext_vector_type(4)));
typedef unsigned short u16x8 __attribute__((ext_vector_type(8)));
typedef unsigned short USHORT;

__device__ __forceinline__ USHORT f2bf(float f) {
    unsigned u = __float_as_uint(f);
    u += 0x7fffu + ((u >> 16) & 1u);
    return (USHORT)(u >> 16);
}

__device__ __forceinline__ f32x4 fz4() { f32x4 z = {0.f, 0.f, 0.f, 0.f}; return z; }

__device__ __forceinline__ bf16x8 ldbf8(const USHORT* p) { return *(const bf16x8*)p; }

__device__ __forceinline__ f32x4 mfma16(bf16x8 a, bf16x8 b, f32x4 c) {
    return __builtin_amdgcn_mfma_f32_16x16x32_bf16(a, b, c, 0, 0, 0);
}

// async global->LDS, 16B per lane; LDS dest is wave-uniform base + lane*16
__device__ __forceinline__ void gload_lds16(const void* g, void* s) {
    __builtin_amdgcn_global_load_lds(
        (const __attribute__((address_space(1))) unsigned int*)g,
        (__attribute__((address_space(3))) unsigned int*)s, 16, 0, 0);
}

// per-wave LDS ordering fence (wave-private alds tile). sched_barrier after the
// waitcnt per guide rule #18.
__device__ __forceinline__ void lds_fence() {
    asm volatile("s_waitcnt lgkmcnt(0)" ::: "memory");
    __builtin_amdgcn_sched_barrier(0);
}

// ---------------- merged prep: X fp32->bf16 + both W transposes ----------------
__global__ __launch_bounds__(256) void prep_kernel(const float* __restrict__ X,
                                                   const float* __restrict__ Wqkv,
                                                   const float* __restrict__ Wout,
                                                   USHORT* __restrict__ Xb,
                                                   USHORT* __restrict__ Wt1,
                                                   USHORT* __restrict__ Wt3) {
    int bid = blockIdx.x;
    if (bid < 2048) {
        int base = (bid * 256 + threadIdx.x) * 8;
        float4 a = *(const float4*)(X + base);
        float4 b = *(const float4*)(X + base + 4);
        u16x8 o;
        o[0] = f2bf(a.x); o[1] = f2bf(a.y); o[2] = f2bf(a.z); o[3] = f2bf(a.w);
        o[4] = f2bf(b.x); o[5] = f2bf(b.y); o[6] = f2bf(b.z); o[7] = f2bf(b.w);
        *(u16x8*)(Xb + base) = o;
    } else if (bid < 3328) {
        int t = (bid - 2048) * 256 + threadIdx.x;   // 0..327679 : 640x512
        int k = t & 511, n = t >> 9;
        Wt1[t] = f2bf(Wqkv[(size_t)k * 1536 + n]);
    } else {
        int t = (bid - 3328) * 256 + threadIdx.x;   // 0..262143 : 512x512
        int k = t & 511, n = t >> 9;
        Wt3[t] = f2bf(Wout[(size_t)k * 512 + n]);
    }
}

// ---------------- fp32 -> bf16 convert (8 elems/thread) ------------------------
__global__ __launch_bounds__(256) void cvt_f32_bf16(const float* __restrict__ src,
                                                    USHORT* __restrict__ dst) {
    int base = (blockIdx.x * 256 + threadIdx.x) * 8;
    float4 a = *(const float4*)(src + base);
    float4 b = *(const float4*)(src + base + 4);
    u16x8 o;
    o[0] = f2bf(a.x); o[1] = f2bf(a.y); o[2] = f2bf(a.z); o[3] = f2bf(a.w);
    o[4] = f2bf(b.x); o[5] = f2bf(b.y); o[6] = f2bf(b.z); o[7] = f2bf(b.w);
    *(u16x8*)(dst + base) = o;
}

// ---------------- m97-style bf16 GEMM: C = A(MxK) * Bt(NxK)^T -------------------
template <bool BF16OUT>
__global__ __launch_bounds__(256) void gemm_bt(const USHORT* __restrict__ A,
                                               const USHORT* __restrict__ Bt,
                                               void* __restrict__ Cv,
                                               int M, int N, int K) {
    __shared__ __align__(16) USHORT Asm[128 * 32];
    __shared__ __align__(16) USHORT Bsm[128 * 32];
    const int tid = threadIdx.x;
    const int wv = tid >> 6, ln = tid & 63;
    const int l16 = ln & 15, quad = ln >> 4;
    const int m0 = blockIdx.x * 128, n0 = blockIdx.y * 128;
    const int wm = (wv >> 1) * 64, wn = (wv & 1) * 64;

    f32x4 acc[4][4];
#pragma unroll
    for (int i = 0; i < 4; ++i)
#pragma unroll
        for (int j = 0; j < 4; ++j) acc[i][j] = fz4();

    const int kTiles = K >> 5;
    for (int kt = 0; kt < kTiles; ++kt) {
        __syncthreads();
#pragma unroll
        for (int i = 0; i < 2; ++i) {
            int cb = wv * 128 + i * 64;
            int c = cb + ln;
            gload_lds16(A + (size_t)(m0 + (c >> 2)) * K + kt * 32 + (c & 3) * 8,
                        &Asm[cb * 8]);
            gload_lds16(Bt + (size_t)(n0 + (c >> 2)) * K + kt * 32 + (c & 3) * 8,
                        &Bsm[cb * 8]);
        }
        __syncthreads();

        bf16x8 af[4], bfr[4];
#pragma unroll
        for (int i = 0; i < 4; ++i)
            af[i] = ldbf8(&Asm[(wm + i * 16 + l16) * 32 + quad * 8]);
#pragma unroll
        for (int j = 0; j < 4; ++j)
            bfr[j] = ldbf8(&Bsm[(wn + j * 16 + l16) * 32 + quad * 8]);
#pragma unroll
        for (int i = 0; i < 4; ++i)
#pragma unroll
            for (int j = 0; j < 4; ++j)
                acc[i][j] = mfma16(af[i], bfr[j], acc[i][j]);
    }

#pragma unroll
    for (int i = 0; i < 4; ++i)
#pragma unroll
        for (int j = 0; j < 4; ++j)
#pragma unroll
            for (int r = 0; r < 4; ++r) {
                size_t row = m0 + wm + i * 16 + quad * 4 + r;
                size_t col = n0 + wn + j * 16 + l16;
                if (BF16OUT)
                    ((USHORT*)Cv)[row * N + col] = f2bf(acc[i][j][r]);
                else
                    ((float*)Cv)[row * N + col] = acc[i][j][r];
            }
}

// ---------------- V transpose: Vt[((b*8+h)*64+d)*1024+k] = P[(b*1024+k)*640+(h+2)*64+d]
__global__ __launch_bounds__(256) void transpose_v(const USHORT* __restrict__ P,
                                                   USHORT* __restrict__ Vt) {
    __shared__ __align__(16) USHORT T[64][72];
    const int t = threadIdx.x;
    const int k0 = blockIdx.x * 64;
    const int hh = blockIdx.y;
    const int b = blockIdx.z;
#pragma unroll
    for (int i = 0; i < 2; ++i) {
        int c = i * 256 + t;
        int kk = c >> 3, d8 = (c & 7) * 8;
        u16x8 v = *(const u16x8*)(P + (size_t)((b << 10) + k0 + kk) * 640 +
                                  (hh + 2) * 64 + d8);
        *(u16x8*)&T[kk][d8] = v;
    }
    __syncthreads();
#pragma unroll
    for (int i = 0; i < 2; ++i) {
        int d = (t >> 3) + i * 32;
        int kk0 = (t & 7) * 8;
        u16x8 v;
#pragma unroll
        for (int j = 0; j < 8; ++j) v[j] = T[kk0 + j][d];
        *(u16x8*)(Vt + (size_t)(((b << 3) + hh) * 64 + d) * 1024 + k0 + kk0) = v;
    }
}

// ---------------- fused attention v4b: shared K/V staging, 74KB LDS ------------
// Grid (h=8, qb=8, kc=4) = 256 blocks, 512 threads (8 waves, 2/SIMD).
// Wave wv computes q-rows [qb*128 + wv*16, +16). kf/vf fragments depend only on
// (h,k0,b,lane) — NOT q — so per 32-key chunk the block stages K (32KB) and
// V (32KB) into LDS ONCE (global_load_lds, m97 stage->barrier->compute) and all
// 8 waves consume them: global K/V traffic drops 8x and the exposed per-load
// L2 latency of v2 becomes pipelined DMA behind one barrier.
// vs v4: alds shrunk 80KB -> 10KB. Softmax normalizes sacc IN PLACE (registers);
// each wave reuses ONE [16][40] tile across the 8 batches in PV
// (write -> lgkmcnt fence -> b128 read -> mfma -> fence for WAR). DS ops are
// per-wave in-order; fences keep waves decoupled (no extra barriers).
__global__ __launch_bounds__(512) void attn_kernel(const USHORT* __restrict__ P,
                                                   const USHORT* __restrict__ Vt,
                                                   float* __restrict__ ctx) {
    const int h = blockIdx.x;
    const int qb = blockIdx.y;
    const int kc = blockIdx.z;                    // 0..3, 256 keys each
    const int tid = threadIdx.x;
    const int wv = tid >> 6;                      // 0..7
    const int lane = tid & 63;
    const int l16 = lane & 15, quad = lane >> 4;
    const int q0 = qb * 128 + wv * 16;

    __shared__ __align__(16) USHORT Kl[16384];        // [b8][ks2][key32][d32] 32KB
    __shared__ __align__(16) USHORT Vl[16384];        // [b8][d64][key32]      32KB
    __shared__ __align__(16) USHORT alds[8][16][40];  // per-wave tile         10KB
    USHORT (*aw)[40] = alds[wv];

    // Q fragments: A[m=l16 (q-row)][k=ks*32+quad*8+j]
    bf16x8 qf[8][2];
#pragma unroll
    for (int b = 0; b < 8; ++b)
#pragma unroll
        for (int ks = 0; ks < 2; ++ks)
            qf[b][ks] = ldbf8(P + (size_t)((b << 10) + q0 + l16) * 640 + h * 64 +
                              ks * 32 + quad * 8);

    f32x4 oacc[8][4];
#pragma unroll
    for (int b = 0; b < 8; ++b)
#pragma unroll
        for (int nt = 0; nt < 4; ++nt) oacc[b][nt] = fz4();

    for (int it = 0; it < 8; ++it) {
        const int k0 = kc * 256 + it * 32;

        __syncthreads();  // previous chunk's LDS reads done; safe to overwrite
        if (wv < 4) {
            // K: 32 loads total; this wave issues 8. g -> (b, ks, key-half)
#pragma unroll
            for (int i = 0; i < 8; ++i) {
                int g = wv * 8 + i;
                int b = g >> 2, ks = (g >> 1) & 1, half = g & 1;
                // lane: key = half*16 + (lane>>2), 16B piece = lane&3
                gload_lds16(P + (size_t)((b << 10) + k0 + half * 16 + (lane >> 2)) * 640 +
                                (h + 1) * 64 + ks * 32 + (lane & 3) * 8,
                            &Kl[((b * 2 + ks) * 32 + half * 16) * 32]);
            }
        } else {
            // V: 32 loads total; this wave issues 8. g -> (b, d-quarter)
#pragma unroll
            for (int i = 0; i < 8; ++i) {
                int g = (wv - 4) * 8 + i;
                int b = g >> 2, dq = g & 3;
                // lane: d = dq*16 + (lane>>2), 16B piece = lane&3
                gload_lds16(Vt + (size_t)(((b << 3) + h) * 64 + dq * 16 + (lane >> 2)) * 1024 +
                                k0 + (lane & 3) * 8,
                            &Vl[(b * 64 + dq * 16) * 32]);
            }
        }
        __syncthreads();  // drains vmcnt: staged K/V visible to all waves

        // ---- scores: sacc[b][nt] covers (16q x 32key), accumulate over ks ----
        f32x4 sacc[8][2];
#pragma unroll
        for (int b = 0; b < 8; ++b) { sacc[b][0] = fz4(); sacc[b][1] = fz4(); }
#pragma unroll
        for (int ks = 0; ks < 2; ++ks)
#pragma unroll
            for (int nt = 0; nt < 2; ++nt) {
                bf16x8 kf[8];
#pragma unroll
                for (int b = 0; b < 8; ++b)
                    kf[b] = ldbf8(&Kl[((b * 2 + ks) * 32 + nt * 16 + l16) * 32 + quad * 8]);
#pragma unroll
                for (int b = 0; b < 8; ++b)
                    sacc[b][nt] = mfma16(qf[b][ks], kf[b], sacc[b][nt]);
            }

        // ---- softmax over batch axis (per-lane), normalize sacc IN PLACE ----
        // scores*scale ~ N(0,0.2^2): exp2 arg |x| < 2 even at 8 sigma.
#pragma unroll
        for (int nt = 0; nt < 2; ++nt)
#pragma unroll
            for (int r = 0; r < 4; ++r) {
                float e[8];
                float Z = 0.f;
#pragma unroll
                for (int b = 0; b < 8; ++b) {
                    // 0.125 (1/sqrt(64)) * log2(e)
                    e[b] = __builtin_amdgcn_exp2f(sacc[b][nt][r] * 0.1803368801f);
                    Z += e[b];
                }
                float inv = __builtin_amdgcn_rcpf(Z);
#pragma unroll
                for (int b = 0; b < 8; ++b)
                    sacc[b][nt][r] = e[b] * inv;
            }

        // ---- PV per batch: stage attn tile via wave-private LDS, then MFMA ----
#pragma unroll
        for (int b = 0; b < 8; ++b) {
            // transpose C-layout (col=l16? no: col=key=l16, row=q=quad*4+r) to
            // A-layout (m=l16=q-row, k=key=quad*8+j) through the [16][40] tile
#pragma unroll
            for (int nt = 0; nt < 2; ++nt)
#pragma unroll
                for (int r = 0; r < 4; ++r)
                    aw[quad * 4 + r][nt * 16 + l16] = f2bf(sacc[b][nt][r]);
            lds_fence();  // ds_write -> ds_read (wave-private)

            bf16x8 af = *(const bf16x8*)&aw[l16][quad * 8];
            bf16x8 vf[4];
#pragma unroll
            for (int nt = 0; nt < 4; ++nt)
                vf[nt] = ldbf8(&Vl[(b * 64 + nt * 16 + l16) * 32 + quad * 8]);
#pragma unroll
            for (int nt = 0; nt < 4; ++nt)
                oacc[b][nt] = mfma16(af, vf[nt], oacc[b][nt]);
            lds_fence();  // WAR: reads drained before next b overwrites tile
        }
    }

    // accumulate partial context (4 kc blocks contend; fire-and-forget atomics)
#pragma unroll
    for (int b = 0; b < 8; ++b)
#pragma unroll
        for (int nt = 0; nt < 4; ++nt)
#pragma unroll
            for (int r = 0; r < 4; ++r) {
                size_t row = (b << 10) + q0 + quad * 4 + r;
                size_t col = h * 64 + nt * 16 + l16;
                unsafeAtomicAdd(&ctx[row * 512 + col], oacc[b][nt][r]);
            }
}

extern "C" void kernel_launch(void* const* d_in, const int* in_sizes, int n_in,
                              void* d_out, int out_size, void* d_ws, size_t ws_size,
                              hipStream_t stream) {
    const float* X = (const float*)d_in[0];     // (8,1024,512)
    const float* Wqkv = (const float*)d_in[1];  // (512,1536) — only cols 0..639 used
    const float* Wout = (const float*)d_in[2];  // (512,512)
    float* out = (float*)d_out;                 // (8,1024,512) fp32

    char* w = (char*)d_ws;
    USHORT* Xb  = (USHORT*)(w);              //  8,388,608 B (reused as CtxB later)
    USHORT* Wt1 = (USHORT*)(w + 8388608);    //    655,360 B  (640x512)
    USHORT* Wt3 = (USHORT*)(w + 9043968);    //    524,288 B  (512x512)
    USHORT* P   = (USHORT*)(w + 9568256);    // 10,485,760 B  (8192x640 bf16)
    USHORT* Vt  = (USHORT*)(w + 20054016);   //  8,388,608 B  (8x8x64x1024 bf16)
    float*  ctx = (float*)(w + 28442624);    // 16,777,216 B  (8192x512 fp32) end=45.2MB
    USHORT* CtxB = Xb;                       // Xb dead after GEMM1

    hipMemsetAsync(ctx, 0, 16777216, stream);
    prep_kernel<<<4352, 256, 0, stream>>>(X, Wqkv, Wout, Xb, Wt1, Wt3);
    // P = Xb @ Wqkv[:, :640]
    gemm_bt<true><<<dim3(64, 5), 256, 0, stream>>>(Xb, Wt1, (void*)P, 8192, 640, 512);
    transpose_v<<<dim3(16, 8, 8), 256, 0, stream>>>(P, Vt);
    attn_kernel<<<dim3(8, 8, 4), 512, 0, stream>>>(P, Vt, ctx);
    cvt_f32_bf16<<<2048, 256, 0, stream>>>(ctx, CtxB);
    // out = ctx @ W_out
    gemm_bt<false><<<dim3(64, 4), 256, 0, stream>>>(CtxB, Wt3, (void*)out, 8192, 512, 512);
}

// Round 4
// 277.839 us; speedup vs baseline: 1.1457x; 1.0273x over previous
//
#include <hip/hip_runtime.h>

typedef __bf16 bf16x8 __attribute__((ext_vector_type(8)));
typedef float  f32x4  __attribute__((ext_vector_type(4)));
typedef unsigned short u16x8 __attribute__((ext_vector_type(8)));
typedef unsigned short USHORT;

__device__ __forceinline__ USHORT f2bf(float f) {
    unsigned u = __float_as_uint(f);
    u += 0x7fffu + ((u >> 16) & 1u);
    return (USHORT)(u >> 16);
}

__device__ __forceinline__ f32x4 fz4() { f32x4 z = {0.f, 0.f, 0.f, 0.f}; return z; }

__device__ __forceinline__ bf16x8 ldbf8(const USHORT* p) { return *(const bf16x8*)p; }

__device__ __forceinline__ f32x4 mfma16(bf16x8 a, bf16x8 b, f32x4 c) {
    return __builtin_amdgcn_mfma_f32_16x16x32_bf16(a, b, c, 0, 0, 0);
}

// async global->LDS, 16B per lane; LDS dest is wave-uniform base + lane*16
__device__ __forceinline__ void gload_lds16(const void* g, void* s) {
    __builtin_amdgcn_global_load_lds(
        (const __attribute__((address_space(1))) unsigned int*)g,
        (__attribute__((address_space(3))) unsigned int*)s, 16, 0, 0);
}

// per-wave LDS ordering fence (wave-private alds tile). sched_barrier after the
// waitcnt per guide rule #18.
__device__ __forceinline__ void lds_fence() {
    asm volatile("s_waitcnt lgkmcnt(0)" ::: "memory");
    __builtin_amdgcn_sched_barrier(0);
}

// ---------------- merged prep: X fp32->bf16 + both W transposes ----------------
__global__ __launch_bounds__(256) void prep_kernel(const float* __restrict__ X,
                                                   const float* __restrict__ Wqkv,
                                                   const float* __restrict__ Wout,
                                                   USHORT* __restrict__ Xb,
                                                   USHORT* __restrict__ Wt1,
                                                   USHORT* __restrict__ Wt3) {
    int bid = blockIdx.x;
    if (bid < 2048) {
        int base = (bid * 256 + threadIdx.x) * 8;
        float4 a = *(const float4*)(X + base);
        float4 b = *(const float4*)(X + base + 4);
        u16x8 o;
        o[0] = f2bf(a.x); o[1] = f2bf(a.y); o[2] = f2bf(a.z); o[3] = f2bf(a.w);
        o[4] = f2bf(b.x); o[5] = f2bf(b.y); o[6] = f2bf(b.z); o[7] = f2bf(b.w);
        *(u16x8*)(Xb + base) = o;
    } else if (bid < 3328) {
        int t = (bid - 2048) * 256 + threadIdx.x;   // 0..327679 : 640x512
        int k = t & 511, n = t >> 9;
        Wt1[t] = f2bf(Wqkv[(size_t)k * 1536 + n]);
    } else {
        int t = (bid - 3328) * 256 + threadIdx.x;   // 0..262143 : 512x512
        int k = t & 511, n = t >> 9;
        Wt3[t] = f2bf(Wout[(size_t)k * 512 + n]);
    }
}

// ---------------- fp32 -> bf16 convert (8 elems/thread) ------------------------
__global__ __launch_bounds__(256) void cvt_f32_bf16(const float* __restrict__ src,
                                                    USHORT* __restrict__ dst) {
    int base = (blockIdx.x * 256 + threadIdx.x) * 8;
    float4 a = *(const float4*)(src + base);
    float4 b = *(const float4*)(src + base + 4);
    u16x8 o;
    o[0] = f2bf(a.x); o[1] = f2bf(a.y); o[2] = f2bf(a.z); o[3] = f2bf(a.w);
    o[4] = f2bf(b.x); o[5] = f2bf(b.y); o[6] = f2bf(b.z); o[7] = f2bf(b.w);
    *(u16x8*)(dst + base) = o;
}

// ---------------- m97-style bf16 GEMM: C = A(MxK) * Bt(NxK)^T -------------------
template <bool BF16OUT>
__global__ __launch_bounds__(256) void gemm_bt(const USHORT* __restrict__ A,
                                               const USHORT* __restrict__ Bt,
                                               void* __restrict__ Cv,
                                               int M, int N, int K) {
    __shared__ __align__(16) USHORT Asm[128 * 32];
    __shared__ __align__(16) USHORT Bsm[128 * 32];
    const int tid = threadIdx.x;
    const int wv = tid >> 6, ln = tid & 63;
    const int l16 = ln & 15, quad = ln >> 4;
    const int m0 = blockIdx.x * 128, n0 = blockIdx.y * 128;
    const int wm = (wv >> 1) * 64, wn = (wv & 1) * 64;

    f32x4 acc[4][4];
#pragma unroll
    for (int i = 0; i < 4; ++i)
#pragma unroll
        for (int j = 0; j < 4; ++j) acc[i][j] = fz4();

    const int kTiles = K >> 5;
    for (int kt = 0; kt < kTiles; ++kt) {
        __syncthreads();
#pragma unroll
        for (int i = 0; i < 2; ++i) {
            int cb = wv * 128 + i * 64;
            int c = cb + ln;
            gload_lds16(A + (size_t)(m0 + (c >> 2)) * K + kt * 32 + (c & 3) * 8,
                        &Asm[cb * 8]);
            gload_lds16(Bt + (size_t)(n0 + (c >> 2)) * K + kt * 32 + (c & 3) * 8,
                        &Bsm[cb * 8]);
        }
        __syncthreads();

        bf16x8 af[4], bfr[4];
#pragma unroll
        for (int i = 0; i < 4; ++i)
            af[i] = ldbf8(&Asm[(wm + i * 16 + l16) * 32 + quad * 8]);
#pragma unroll
        for (int j = 0; j < 4; ++j)
            bfr[j] = ldbf8(&Bsm[(wn + j * 16 + l16) * 32 + quad * 8]);
#pragma unroll
        for (int i = 0; i < 4; ++i)
#pragma unroll
            for (int j = 0; j < 4; ++j)
                acc[i][j] = mfma16(af[i], bfr[j], acc[i][j]);
    }

#pragma unroll
    for (int i = 0; i < 4; ++i)
#pragma unroll
        for (int j = 0; j < 4; ++j)
#pragma unroll
            for (int r = 0; r < 4; ++r) {
                size_t row = m0 + wm + i * 16 + quad * 4 + r;
                size_t col = n0 + wn + j * 16 + l16;
                if (BF16OUT)
                    ((USHORT*)Cv)[row * N + col] = f2bf(acc[i][j][r]);
                else
                    ((float*)Cv)[row * N + col] = acc[i][j][r];
            }
}

// ---------------- V transpose: Vt[((b*8+h)*64+d)*1024+k] = P[(b*1024+k)*640+(h+2)*64+d]
__global__ __launch_bounds__(256) void transpose_v(const USHORT* __restrict__ P,
                                                   USHORT* __restrict__ Vt) {
    __shared__ __align__(16) USHORT T[64][72];
    const int t = threadIdx.x;
    const int k0 = blockIdx.x * 64;
    const int hh = blockIdx.y;
    const int b = blockIdx.z;
#pragma unroll
    for (int i = 0; i < 2; ++i) {
        int c = i * 256 + t;
        int kk = c >> 3, d8 = (c & 7) * 8;
        u16x8 v = *(const u16x8*)(P + (size_t)((b << 10) + k0 + kk) * 640 +
                                  (hh + 2) * 64 + d8);
        *(u16x8*)&T[kk][d8] = v;
    }
    __syncthreads();
#pragma unroll
    for (int i = 0; i < 2; ++i) {
        int d = (t >> 3) + i * 32;
        int kk0 = (t & 7) * 8;
        u16x8 v;
#pragma unroll
        for (int j = 0; j < 8; ++j) v[j] = T[kk0 + j][d];
        *(u16x8*)(Vt + (size_t)(((b << 3) + hh) * 64 + d) * 1024 + k0 + kk0) = v;
    }
}

// ---------------- fused attention v5 -------------------------------------------
// = v4b (shared K/V staging, 8 waves x 16q, kc=4) + two fixes driven by r3 PMC:
//
// (1) CONFLICT-FREE K/V LDS MAP. v4b's fragment read put byte l16*64+quad*16 ->
//     8 lanes/bank on every ds_read_b128 (SQ_LDS_BANK_CONFLICT 4.7M ~= 70us).
//     gload_lds dest is linear (base+lane*16), but the staging lane->GLOBAL
//     address map is free. New map: 16B chunk at offset o holds
//     (piece=(o>>4)&3, key=(o&15)+(o>>6)*16). Fragment read becomes
//     base + nt*512 + lane*8  -- linear in lane -> conflict-free, and the
//     compiler folds nt*512 into ds_read offset immediates. Same bytes, same
//     fragments (bijection checked both directions). Applied to K and V.
// (2) DOUBLE-BUFFERED STAGING (T3 minimal 2-phase). Kl[2]/Vl[2] (128KB+10KB
//     alds = 138KB LDS). Per it: issue stage(it+1) into idle buffer FIRST,
//     compute current, one __syncthreads (its vmcnt-drain finds the prefetch
//     already landed under the compute). Buffer written at it was last read
//     before the barrier ending it-1 -> safe.
__global__ __launch_bounds__(512) void attn_kernel(const USHORT* __restrict__ P,
                                                   const USHORT* __restrict__ Vt,
                                                   float* __restrict__ ctx) {
    const int h = blockIdx.x;
    const int qb = blockIdx.y;
    const int kc = blockIdx.z;                    // 0..3, 256 keys each
    const int tid = threadIdx.x;
    const int wv = tid >> 6;                      // 0..7
    const int lane = tid & 63;
    const int l16 = lane & 15, quad = lane >> 4;
    const int q0 = qb * 128 + wv * 16;

    // Kl chunk map per (b,ks) 2KB region: off16B = (key>>4)*64 + piece*16 + (key&15)
    // Vl chunk map per (b)    4KB region: off16B = (d>>4)*64  + piece*16 + (d&15)
    __shared__ __align__(16) USHORT Kl[2][16384];     // 64KB
    __shared__ __align__(16) USHORT Vl[2][16384];     // 64KB
    __shared__ __align__(16) USHORT alds[8][16][40];  // per-wave tile 10KB
    USHORT (*aw)[40] = alds[wv];

    // Q fragments: A[m=l16 (q-row)][k=ks*32+quad*8+j]
    bf16x8 qf[8][2];
#pragma unroll
    for (int b = 0; b < 8; ++b)
#pragma unroll
        for (int ks = 0; ks < 2; ++ks)
            qf[b][ks] = ldbf8(P + (size_t)((b << 10) + q0 + l16) * 640 + h * 64 +
                              ks * 32 + quad * 8);

    f32x4 oacc[8][4];
#pragma unroll
    for (int b = 0; b < 8; ++b)
#pragma unroll
        for (int nt = 0; nt < 4; ++nt) oacc[b][nt] = fz4();

    // ---- staging: 64 gload_lds total (8/wave); wv<4 -> K, wv>=4 -> V ----
    // K instr (b,ks,half): lane s loads (key=half*16+(s&15), piece=s>>4)
    //   -> dest chunks half*64 + s  (contiguous 1KB, wave-uniform base)
    // V instr (b,dq):      lane s loads (d = dq*16+(s&15),  piece=s>>4)
    auto stage = [&](int k0s, int buf) {
        if (wv < 4) {
#pragma unroll
            for (int i = 0; i < 8; ++i) {
                int g = wv * 8 + i;
                int b = g >> 2, ks = (g >> 1) & 1, half = g & 1;
                gload_lds16(P + (size_t)((b << 10) + k0s + half * 16 + (lane & 15)) * 640 +
                                (h + 1) * 64 + ks * 32 + (lane >> 4) * 8,
                            &Kl[buf][(b * 2 + ks) * 1024 + half * 512]);
            }
        } else {
#pragma unroll
            for (int i = 0; i < 8; ++i) {
                int g = (wv - 4) * 8 + i;
                int b = g >> 2, dq = g & 3;
                gload_lds16(Vt + (size_t)(((b << 3) + h) * 64 + dq * 16 + (lane & 15)) * 1024 +
                                k0s + (lane >> 4) * 8,
                            &Vl[buf][b * 2048 + dq * 512]);
            }
        }
    };

    const int kbase = kc * 256;
    stage(kbase, 0);
    __syncthreads();  // drains vmcnt: buffer 0 ready

    int buf = 0;
    for (int it = 0; it < 8; ++it) {
        if (it < 7) stage(kbase + (it + 1) * 32, buf ^ 1);  // prefetch under compute

        const USHORT* Kb = Kl[buf];
        const USHORT* Vb = Vl[buf];

        // ---- scores: sacc[b][nt] covers (16q x 32key), accumulate over ks ----
        f32x4 sacc[8][2];
#pragma unroll
        for (int b = 0; b < 8; ++b) { sacc[b][0] = fz4(); sacc[b][1] = fz4(); }
#pragma unroll
        for (int ks = 0; ks < 2; ++ks)
#pragma unroll
            for (int nt = 0; nt < 2; ++nt) {
                bf16x8 kf[8];
#pragma unroll
                for (int b = 0; b < 8; ++b)
                    kf[b] = ldbf8(&Kb[(b * 2 + ks) * 1024 + nt * 512 + lane * 8]);
#pragma unroll
                for (int b = 0; b < 8; ++b)
                    sacc[b][nt] = mfma16(qf[b][ks], kf[b], sacc[b][nt]);
            }

        // ---- softmax over batch axis (per-lane), normalize sacc IN PLACE ----
        // scores*scale ~ N(0,0.2^2): exp2 arg |x| < 2 even at 8 sigma.
#pragma unroll
        for (int nt = 0; nt < 2; ++nt)
#pragma unroll
            for (int r = 0; r < 4; ++r) {
                float e[8];
                float Z = 0.f;
#pragma unroll
                for (int b = 0; b < 8; ++b) {
                    // 0.125 (1/sqrt(64)) * log2(e)
                    e[b] = __builtin_amdgcn_exp2f(sacc[b][nt][r] * 0.1803368801f);
                    Z += e[b];
                }
                float inv = __builtin_amdgcn_rcpf(Z);
#pragma unroll
                for (int b = 0; b < 8; ++b)
                    sacc[b][nt][r] = e[b] * inv;
            }

        // ---- PV per batch: stage attn tile via wave-private LDS, then MFMA ----
#pragma unroll
        for (int b = 0; b < 8; ++b) {
            // C-layout (col=key=l16, row=q=quad*4+r) -> A-layout (m=q=l16,
            // k=key=quad*8+j) through the wave-private [16][40] tile
#pragma unroll
            for (int nt = 0; nt < 2; ++nt)
#pragma unroll
                for (int r = 0; r < 4; ++r)
                    aw[quad * 4 + r][nt * 16 + l16] = f2bf(sacc[b][nt][r]);
            lds_fence();  // ds_write -> ds_read (wave-private)

            bf16x8 af = *(const bf16x8*)&aw[l16][quad * 8];
            bf16x8 vf[4];
#pragma unroll
            for (int nt = 0; nt < 4; ++nt)
                vf[nt] = ldbf8(&Vb[b * 2048 + nt * 512 + lane * 8]);
#pragma unroll
            for (int nt = 0; nt < 4; ++nt)
                oacc[b][nt] = mfma16(af, vf[nt], oacc[b][nt]);
            lds_fence();  // WAR: reads drained before next b overwrites tile
        }

        __syncthreads();  // drains vmcnt: prefetched buffer ready; LDS reads done
        buf ^= 1;
    }

    // accumulate partial context (4 kc blocks contend; fire-and-forget atomics)
#pragma unroll
    for (int b = 0; b < 8; ++b)
#pragma unroll
        for (int nt = 0; nt < 4; ++nt)
#pragma unroll
            for (int r = 0; r < 4; ++r) {
                size_t row = (b << 10) + q0 + quad * 4 + r;
                size_t col = h * 64 + nt * 16 + l16;
                unsafeAtomicAdd(&ctx[row * 512 + col], oacc[b][nt][r]);
            }
}

extern "C" void kernel_launch(void* const* d_in, const int* in_sizes, int n_in,
                              void* d_out, int out_size, void* d_ws, size_t ws_size,
                              hipStream_t stream) {
    const float* X = (const float*)d_in[0];     // (8,1024,512)
    const float* Wqkv = (const float*)d_in[1];  // (512,1536) — only cols 0..639 used
    const float* Wout = (const float*)d_in[2];  // (512,512)
    float* out = (float*)d_out;                 // (8,1024,512) fp32

    char* w = (char*)d_ws;
    USHORT* Xb  = (USHORT*)(w);              //  8,388,608 B (reused as CtxB later)
    USHORT* Wt1 = (USHORT*)(w + 8388608);    //    655,360 B  (640x512)
    USHORT* Wt3 = (USHORT*)(w + 9043968);    //    524,288 B  (512x512)
    USHORT* P   = (USHORT*)(w + 9568256);    // 10,485,760 B  (8192x640 bf16)
    USHORT* Vt  = (USHORT*)(w + 20054016);   //  8,388,608 B  (8x8x64x1024 bf16)
    float*  ctx = (float*)(w + 28442624);    // 16,777,216 B  (8192x512 fp32) end=45.2MB
    USHORT* CtxB = Xb;                       // Xb dead after GEMM1

    hipMemsetAsync(ctx, 0, 16777216, stream);
    prep_kernel<<<4352, 256, 0, stream>>>(X, Wqkv, Wout, Xb, Wt1, Wt3);
    // P = Xb @ Wqkv[:, :640]
    gemm_bt<true><<<dim3(64, 5), 256, 0, stream>>>(Xb, Wt1, (void*)P, 8192, 640, 512);
    transpose_v<<<dim3(16, 8, 8), 256, 0, stream>>>(P, Vt);
    attn_kernel<<<dim3(8, 8, 4), 512, 0, stream>>>(P, Vt, ctx);
    cvt_f32_bf16<<<2048, 256, 0, stream>>>(ctx, CtxB);
    // out = ctx @ W_out
    gemm_bt<false><<<dim3(64, 4), 256, 0, stream>>>(CtxB, Wt3, (void*)out, 8192, 512, 512);
}

// Round 5
// 235.678 us; speedup vs baseline: 1.3507x; 1.1789x over previous
//
#include <hip/hip_runtime.h>

typedef __bf16 bf16x8 __attribute__((ext_vector_type(8)));
typedef float  f32x4  __attribute__((ext_vector_type(4)));
typedef unsigned short u16x8 __attribute__((ext_vector_type(8)));
typedef unsigned short USHORT;

__device__ __forceinline__ USHORT f2bf(float f) {
    unsigned u = __float_as_uint(f);
    u += 0x7fffu + ((u >> 16) & 1u);
    return (USHORT)(u >> 16);
}

__device__ __forceinline__ float bf2f(USHORT v) {
    return __uint_as_float((unsigned)v << 16);
}

__device__ __forceinline__ f32x4 fz4() { f32x4 z = {0.f, 0.f, 0.f, 0.f}; return z; }

__device__ __forceinline__ bf16x8 ldbf8(const USHORT* p) { return *(const bf16x8*)p; }

__device__ __forceinline__ f32x4 mfma16(bf16x8 a, bf16x8 b, f32x4 c) {
    return __builtin_amdgcn_mfma_f32_16x16x32_bf16(a, b, c, 0, 0, 0);
}

// async global->LDS, 16B per lane; LDS dest is wave-uniform base + lane*16
__device__ __forceinline__ void gload_lds16(const void* g, void* s) {
    __builtin_amdgcn_global_load_lds(
        (const __attribute__((address_space(1))) unsigned int*)g,
        (__attribute__((address_space(3))) unsigned int*)s, 16, 0, 0);
}

// per-wave LDS ordering fence (wave-private alds tile). sched_barrier after the
// waitcnt per guide rule #18.
__device__ __forceinline__ void lds_fence() {
    asm volatile("s_waitcnt lgkmcnt(0)" ::: "memory");
    __builtin_amdgcn_sched_barrier(0);
}

// ---------------- merged prep: X fp32->bf16 + both W transposes ----------------
__global__ __launch_bounds__(256) void prep_kernel(const float* __restrict__ X,
                                                   const float* __restrict__ Wqkv,
                                                   const float* __restrict__ Wout,
                                                   USHORT* __restrict__ Xb,
                                                   USHORT* __restrict__ Wt1,
                                                   USHORT* __restrict__ Wt3) {
    int bid = blockIdx.x;
    if (bid < 2048) {
        int base = (bid * 256 + threadIdx.x) * 8;
        float4 a = *(const float4*)(X + base);
        float4 b = *(const float4*)(X + base + 4);
        u16x8 o;
        o[0] = f2bf(a.x); o[1] = f2bf(a.y); o[2] = f2bf(a.z); o[3] = f2bf(a.w);
        o[4] = f2bf(b.x); o[5] = f2bf(b.y); o[6] = f2bf(b.z); o[7] = f2bf(b.w);
        *(u16x8*)(Xb + base) = o;
    } else if (bid < 3328) {
        int t = (bid - 2048) * 256 + threadIdx.x;   // 0..327679 : 640x512
        int k = t & 511, n = t >> 9;
        Wt1[t] = f2bf(Wqkv[(size_t)k * 1536 + n]);
    } else {
        int t = (bid - 3328) * 256 + threadIdx.x;   // 0..262143 : 512x512
        int k = t & 511, n = t >> 9;
        Wt3[t] = f2bf(Wout[(size_t)k * 512 + n]);
    }
}

// ---------------- 4-way partial-ctx reduce: o = bf16(sum fp32(parts)) ----------
// In-place safe with o == a (each thread reads its 8 elems before writing them).
__global__ __launch_bounds__(256) void reduce4(const USHORT* __restrict__ a,
                                               const USHORT* __restrict__ b,
                                               const USHORT* __restrict__ c,
                                               const USHORT* __restrict__ d,
                                               USHORT* __restrict__ o) {
    int base = (blockIdx.x * 256 + threadIdx.x) * 8;
    u16x8 va = *(const u16x8*)(a + base);
    u16x8 vb = *(const u16x8*)(b + base);
    u16x8 vc = *(const u16x8*)(c + base);
    u16x8 vd = *(const u16x8*)(d + base);
    u16x8 out;
#pragma unroll
    for (int j = 0; j < 8; ++j)
        out[j] = f2bf(bf2f(va[j]) + bf2f(vb[j]) + bf2f(vc[j]) + bf2f(vd[j]));
    *(u16x8*)(o + base) = out;
}

// ---------------- m97-style bf16 GEMM: C = A(MxK) * Bt(NxK)^T -------------------
template <bool BF16OUT>
__global__ __launch_bounds__(256) void gemm_bt(const USHORT* __restrict__ A,
                                               const USHORT* __restrict__ Bt,
                                               void* __restrict__ Cv,
                                               int M, int N, int K) {
    __shared__ __align__(16) USHORT Asm[128 * 32];
    __shared__ __align__(16) USHORT Bsm[128 * 32];
    const int tid = threadIdx.x;
    const int wv = tid >> 6, ln = tid & 63;
    const int l16 = ln & 15, quad = ln >> 4;
    const int m0 = blockIdx.x * 128, n0 = blockIdx.y * 128;
    const int wm = (wv >> 1) * 64, wn = (wv & 1) * 64;

    f32x4 acc[4][4];
#pragma unroll
    for (int i = 0; i < 4; ++i)
#pragma unroll
        for (int j = 0; j < 4; ++j) acc[i][j] = fz4();

    const int kTiles = K >> 5;
    for (int kt = 0; kt < kTiles; ++kt) {
        __syncthreads();
#pragma unroll
        for (int i = 0; i < 2; ++i) {
            int cb = wv * 128 + i * 64;
            int c = cb + ln;
            gload_lds16(A + (size_t)(m0 + (c >> 2)) * K + kt * 32 + (c & 3) * 8,
                        &Asm[cb * 8]);
            gload_lds16(Bt + (size_t)(n0 + (c >> 2)) * K + kt * 32 + (c & 3) * 8,
                        &Bsm[cb * 8]);
        }
        __syncthreads();

        bf16x8 af[4], bfr[4];
#pragma unroll
        for (int i = 0; i < 4; ++i)
            af[i] = ldbf8(&Asm[(wm + i * 16 + l16) * 32 + quad * 8]);
#pragma unroll
        for (int j = 0; j < 4; ++j)
            bfr[j] = ldbf8(&Bsm[(wn + j * 16 + l16) * 32 + quad * 8]);
#pragma unroll
        for (int i = 0; i < 4; ++i)
#pragma unroll
            for (int j = 0; j < 4; ++j)
                acc[i][j] = mfma16(af[i], bfr[j], acc[i][j]);
    }

#pragma unroll
    for (int i = 0; i < 4; ++i)
#pragma unroll
        for (int j = 0; j < 4; ++j)
#pragma unroll
            for (int r = 0; r < 4; ++r) {
                size_t row = m0 + wm + i * 16 + quad * 4 + r;
                size_t col = n0 + wn + j * 16 + l16;
                if (BF16OUT)
                    ((USHORT*)Cv)[row * N + col] = f2bf(acc[i][j][r]);
                else
                    ((float*)Cv)[row * N + col] = acc[i][j][r];
            }
}

// ---------------- V transpose: Vt[((b*8+h)*64+d)*1024+k] = P[(b*1024+k)*640+(h+2)*64+d]
__global__ __launch_bounds__(256) void transpose_v(const USHORT* __restrict__ P,
                                                   USHORT* __restrict__ Vt) {
    __shared__ __align__(16) USHORT T[64][72];
    const int t = threadIdx.x;
    const int k0 = blockIdx.x * 64;
    const int hh = blockIdx.y;
    const int b = blockIdx.z;
#pragma unroll
    for (int i = 0; i < 2; ++i) {
        int c = i * 256 + t;
        int kk = c >> 3, d8 = (c & 7) * 8;
        u16x8 v = *(const u16x8*)(P + (size_t)((b << 10) + k0 + kk) * 640 +
                                  (hh + 2) * 64 + d8);
        *(u16x8*)&T[kk][d8] = v;
    }
    __syncthreads();
#pragma unroll
    for (int i = 0; i < 2; ++i) {
        int d = (t >> 3) + i * 32;
        int kk0 = (t & 7) * 8;
        u16x8 v;
#pragma unroll
        for (int j = 0; j < 8; ++j) v[j] = T[kk0 + j][d];
        *(u16x8*)(Vt + (size_t)(((b << 3) + hh) * 64 + d) * 1024 + k0 + kk0) = v;
    }
}

// ---------------- fused attention v6 -------------------------------------------
// = v5 (shared K/V staging, conflict-free LDS map, double-buffer) with the
// epilogue changed from fp32 global ATOMICS to plain bf16 stores into a per-kc
// partial buffer. r4 PMC showed the atomic path was ~270MB of the 430MB total
// L2-external traffic (WRITE 213MB vs 67MB payload = RMW line ping-pong across
// the 4 contending kc blocks, plus ~60MB of ctx line fills). Each (wave,kc)
// owns its 16q x 64d x 8b tile exclusively -> no contention, write-once.
// A reduce4 kernel folds the 4 partials (fp32 accum) into CtxB for GEMM2,
// replacing cvt_f32_bf16; ctx memset is gone too.
__global__ __launch_bounds__(512) void attn_kernel(const USHORT* __restrict__ P,
                                                   const USHORT* __restrict__ Vt,
                                                   USHORT* __restrict__ pt0,
                                                   USHORT* __restrict__ pt1,
                                                   USHORT* __restrict__ pt2,
                                                   USHORT* __restrict__ pt3) {
    const int h = blockIdx.x;
    const int qb = blockIdx.y;
    const int kc = blockIdx.z;                    // 0..3, 256 keys each
    const int tid = threadIdx.x;
    const int wv = tid >> 6;                      // 0..7
    const int lane = tid & 63;
    const int l16 = lane & 15, quad = lane >> 4;
    const int q0 = qb * 128 + wv * 16;

    // Kl chunk map per (b,ks) 2KB region: off16B = (key>>4)*64 + piece*16 + (key&15)
    // Vl chunk map per (b)    4KB region: off16B = (d>>4)*64  + piece*16 + (d&15)
    __shared__ __align__(16) USHORT Kl[2][16384];     // 64KB
    __shared__ __align__(16) USHORT Vl[2][16384];     // 64KB
    __shared__ __align__(16) USHORT alds[8][16][40];  // per-wave tile 10KB
    USHORT (*aw)[40] = alds[wv];

    // Q fragments: A[m=l16 (q-row)][k=ks*32+quad*8+j]
    bf16x8 qf[8][2];
#pragma unroll
    for (int b = 0; b < 8; ++b)
#pragma unroll
        for (int ks = 0; ks < 2; ++ks)
            qf[b][ks] = ldbf8(P + (size_t)((b << 10) + q0 + l16) * 640 + h * 64 +
                              ks * 32 + quad * 8);

    f32x4 oacc[8][4];
#pragma unroll
    for (int b = 0; b < 8; ++b)
#pragma unroll
        for (int nt = 0; nt < 4; ++nt) oacc[b][nt] = fz4();

    // ---- staging: 64 gload_lds total (8/wave); wv<4 -> K, wv>=4 -> V ----
    // K instr (b,ks,half): lane s loads (key=half*16+(s&15), piece=s>>4)
    //   -> dest chunks half*64 + s  (contiguous 1KB, wave-uniform base)
    // V instr (b,dq):      lane s loads (d = dq*16+(s&15),  piece=s>>4)
    auto stage = [&](int k0s, int buf) {
        if (wv < 4) {
#pragma unroll
            for (int i = 0; i < 8; ++i) {
                int g = wv * 8 + i;
                int b = g >> 2, ks = (g >> 1) & 1, half = g & 1;
                gload_lds16(P + (size_t)((b << 10) + k0s + half * 16 + (lane & 15)) * 640 +
                                (h + 1) * 64 + ks * 32 + (lane >> 4) * 8,
                            &Kl[buf][(b * 2 + ks) * 1024 + half * 512]);
            }
        } else {
#pragma unroll
            for (int i = 0; i < 8; ++i) {
                int g = (wv - 4) * 8 + i;
                int b = g >> 2, dq = g & 3;
                gload_lds16(Vt + (size_t)(((b << 3) + h) * 64 + dq * 16 + (lane & 15)) * 1024 +
                                k0s + (lane >> 4) * 8,
                            &Vl[buf][b * 2048 + dq * 512]);
            }
        }
    };

    const int kbase = kc * 256;
    stage(kbase, 0);
    __syncthreads();  // drains vmcnt: buffer 0 ready

    int buf = 0;
    for (int it = 0; it < 8; ++it) {
        if (it < 7) stage(kbase + (it + 1) * 32, buf ^ 1);  // prefetch under compute

        const USHORT* Kb = Kl[buf];
        const USHORT* Vb = Vl[buf];

        // ---- scores: sacc[b][nt] covers (16q x 32key), accumulate over ks ----
        f32x4 sacc[8][2];
#pragma unroll
        for (int b = 0; b < 8; ++b) { sacc[b][0] = fz4(); sacc[b][1] = fz4(); }
#pragma unroll
        for (int ks = 0; ks < 2; ++ks)
#pragma unroll
            for (int nt = 0; nt < 2; ++nt) {
                bf16x8 kf[8];
#pragma unroll
                for (int b = 0; b < 8; ++b)
                    kf[b] = ldbf8(&Kb[(b * 2 + ks) * 1024 + nt * 512 + lane * 8]);
#pragma unroll
                for (int b = 0; b < 8; ++b)
                    sacc[b][nt] = mfma16(qf[b][ks], kf[b], sacc[b][nt]);
            }

        // ---- softmax over batch axis (per-lane), normalize sacc IN PLACE ----
        // scores*scale ~ N(0,0.2^2): exp2 arg |x| < 2 even at 8 sigma.
#pragma unroll
        for (int nt = 0; nt < 2; ++nt)
#pragma unroll
            for (int r = 0; r < 4; ++r) {
                float e[8];
                float Z = 0.f;
#pragma unroll
                for (int b = 0; b < 8; ++b) {
                    // 0.125 (1/sqrt(64)) * log2(e)
                    e[b] = __builtin_amdgcn_exp2f(sacc[b][nt][r] * 0.1803368801f);
                    Z += e[b];
                }
                float inv = __builtin_amdgcn_rcpf(Z);
#pragma unroll
                for (int b = 0; b < 8; ++b)
                    sacc[b][nt][r] = e[b] * inv;
            }

        // ---- PV per batch: stage attn tile via wave-private LDS, then MFMA ----
#pragma unroll
        for (int b = 0; b < 8; ++b) {
            // C-layout (col=key=l16, row=q=quad*4+r) -> A-layout (m=q=l16,
            // k=key=quad*8+j) through the wave-private [16][40] tile
#pragma unroll
            for (int nt = 0; nt < 2; ++nt)
#pragma unroll
                for (int r = 0; r < 4; ++r)
                    aw[quad * 4 + r][nt * 16 + l16] = f2bf(sacc[b][nt][r]);
            lds_fence();  // ds_write -> ds_read (wave-private)

            bf16x8 af = *(const bf16x8*)&aw[l16][quad * 8];
            bf16x8 vf[4];
#pragma unroll
            for (int nt = 0; nt < 4; ++nt)
                vf[nt] = ldbf8(&Vb[b * 2048 + nt * 512 + lane * 8]);
#pragma unroll
            for (int nt = 0; nt < 4; ++nt)
                oacc[b][nt] = mfma16(af, vf[nt], oacc[b][nt]);
            lds_fence();  // WAR: reads drained before next b overwrites tile
        }

        __syncthreads();  // drains vmcnt: prefetched buffer ready; LDS reads done
        buf ^= 1;
    }

    // ---- epilogue: plain bf16 stores into this kc's partial buffer ----
    // (wave,kc) owns its 16q x 64d x 8b tile exclusively: no contention.
    USHORT* part = (kc == 0) ? pt0 : (kc == 1) ? pt1 : (kc == 2) ? pt2 : pt3;
#pragma unroll
    for (int b = 0; b < 8; ++b)
#pragma unroll
        for (int nt = 0; nt < 4; ++nt)
#pragma unroll
            for (int r = 0; r < 4; ++r) {
                size_t row = (b << 10) + q0 + quad * 4 + r;
                size_t col = h * 64 + nt * 16 + l16;
                part[row * 512 + col] = f2bf(oacc[b][nt][r]);
            }
}

extern "C" void kernel_launch(void* const* d_in, const int* in_sizes, int n_in,
                              void* d_out, int out_size, void* d_ws, size_t ws_size,
                              hipStream_t stream) {
    const float* X = (const float*)d_in[0];     // (8,1024,512)
    const float* Wqkv = (const float*)d_in[1];  // (512,1536) — only cols 0..639 used
    const float* Wout = (const float*)d_in[2];  // (512,512)
    float* out = (float*)d_out;                 // (8,1024,512) fp32

    char* w = (char*)d_ws;
    USHORT* Xb  = (USHORT*)(w);              //  8,388,608 B (reused as parts[0]/CtxB)
    USHORT* Wt1 = (USHORT*)(w + 8388608);    //    655,360 B  (640x512)
    USHORT* Wt3 = (USHORT*)(w + 9043968);    //    524,288 B  (512x512)
    USHORT* P   = (USHORT*)(w + 9568256);    // 10,485,760 B  (8192x640 bf16)
    USHORT* Vt  = (USHORT*)(w + 20054016);   //  8,388,608 B  (8x8x64x1024 bf16)
    USHORT* pt1 = (USHORT*)(w + 28442624);   //  8,388,608 B  partial ctx (kc=1)
    USHORT* pt2 = (USHORT*)(w + 36831232);   //  8,388,608 B  partial ctx (kc=2)
    USHORT* pt3 = (USHORT*)(w + 45219840);   //  8,388,608 B  partial ctx (kc=3) end=53.6MB
    USHORT* pt0 = Xb;                        // Xb dead after GEMM1; also reduce4 output
    USHORT* CtxB = Xb;

    prep_kernel<<<4352, 256, 0, stream>>>(X, Wqkv, Wout, Xb, Wt1, Wt3);
    // P = Xb @ Wqkv[:, :640]
    gemm_bt<true><<<dim3(64, 5), 256, 0, stream>>>(Xb, Wt1, (void*)P, 8192, 640, 512);
    transpose_v<<<dim3(16, 8, 8), 256, 0, stream>>>(P, Vt);
    attn_kernel<<<dim3(8, 8, 4), 512, 0, stream>>>(P, Vt, pt0, pt1, pt2, pt3);
    // CtxB = sum of partials (in-place over pt0, fp32 accumulation)
    reduce4<<<2048, 256, 0, stream>>>(pt0, pt1, pt2, pt3, CtxB);
    // out = ctx @ W_out
    gemm_bt<false><<<dim3(64, 4), 256, 0, stream>>>(CtxB, Wt3, (void*)out, 8192, 512, 512);
}